// Round 8
// baseline (169.300 us; speedup 1.0000x reference)
//
#include <hip/hip_runtime.h>

#define NT 128
#define TPW 32   // tokens per wave; 2 independent waves per block, no barriers

#define GL16(gp, lp) __builtin_amdgcn_global_load_lds( \
    (const __attribute__((address_space(1))) void*)(gp), \
    (__attribute__((address_space(3))) void*)(lp), 16, 0, 0)
#define GL4(gp, lp) __builtin_amdgcn_global_load_lds( \
    (const __attribute__((address_space(1))) void*)(gp), \
    (__attribute__((address_space(3))) void*)(lp), 4, 0, 0)
#define WAITVM(N) do { \
    asm volatile("s_waitcnt vmcnt(" #N ")" ::: "memory"); \
    __builtin_amdgcn_sched_barrier(0); \
} while (0)
#define WAITLG() do { \
    asm volatile("s_waitcnt lgkmcnt(0)" ::: "memory"); \
    __builtin_amdgcn_sched_barrier(0); \
} while (0)

#if defined(__has_builtin)
# if __has_builtin(__builtin_amdgcn_exp2f)
#  define EXP2F(x) __builtin_amdgcn_exp2f(x)
# else
#  define EXP2F(x) exp2f(x)
# endif
#else
# define EXP2F(x) exp2f(x)
#endif

// 32 tokens x 45 floats = 360 float4 -> LDS: 5 full GL16 + one 40-lane partial.
__device__ __forceinline__ void stage45(const float* __restrict__ g, float* lds, int lane) {
    const float4* g4 = (const float4*)g;
    #pragma unroll
    for (int it = 0; it < 5; ++it)
        GL16(g4 + it * 64 + lane, lds + it * 256);
    if (lane < 40) GL16(g4 + 320 + lane, lds + 1280);
}

// One dist row r for this wave's 32 tokens = 480 floats: 7 full GL4 + one 32-lane partial.
// m = it*64+lane ; tok=m/15 ; j=m%15 ; off = tok*225+j (row offset folded into dr).
__device__ __forceinline__ void stage_row(const float* __restrict__ dr, float* slot,
                                          int off0, int j0, int lane) {
    int off = off0, j = j0;
    #pragma unroll
    for (int it = 0; it < 7; ++it) {
        GL4(dr + off, slot + it * 64);
        j += 4;
        bool w = (j >= 15);
        j -= w ? 15 : 0;
        off += w ? 1114 : 904;      // wrap: 5*225-11 ; no-wrap: 4*225+4
    }
    if (lane < TPW) GL4(dr + off, slot + 448);   // m = 448+lane, lanes 0-31 only
}

// dst[h][n] = (|.|) sum_d row[d*15+n]*w[h*3+d] + bb[h]
template <bool ABS>
__device__ __forceinline__ void projr(const float* row, const float w[9], const float bb[3],
                                      float dst[3][15]) {
    #pragma unroll
    for (int n = 0; n < 15; ++n) {
        float x0 = row[n], x1 = row[15 + n], x2 = row[30 + n];
        #pragma unroll
        for (int h = 0; h < 3; ++h) {
            float y = fmaf(x2, w[h*3+2], fmaf(x1, w[h*3+1], fmaf(x0, w[h*3+0], bb[h])));
            dst[h][n] = ABS ? fabsf(y) : y;
        }
    }
}

// Ring-5 slot for dist row r: {D0, D1, B0, B1, B2}
#define SLOTP(r) ((r) % 5 == 0 ? myD : (r) % 5 == 1 ? myD + 480 : myBuf + ((r) % 5 - 2) * 480)

// Phase p: counted wait for row p, consume (lanes 0-31), issue row p+5 into same slot.
#define PHASE(p, WN) do { \
    WAITVM(WN); \
    if (lane < TPW) { \
      const float* sl = SLOTP(p) + lane * 15; \
      _Pragma("unroll") \
      for (int jj = 0; jj < 15; ++jj) { \
        float dd = sl[jj]; \
        concat[(p)*3 + 0] = fmaf(dd, vv[0][jj], concat[(p)*3 + 0]); \
        concat[(p)*3 + 1] = fmaf(dd, vv[1][jj], concat[(p)*3 + 1]); \
        concat[(p)*3 + 2] = fmaf(dd, vv[2][jj], concat[(p)*3 + 2]); \
      } } \
    if ((p) <= 9) { WAITLG(); stage_row(dbase + ((p)+5)*15, SLOTP(p), off0, j0, lane); } \
} while (0)

__global__ __launch_bounds__(NT, 4) void mha_spatial_kernel(
    const float* __restrict__ q, const float* __restrict__ k, const float* __restrict__ v,
    const float* __restrict__ dist,
    const float* __restrict__ Wq, const float* __restrict__ bq,
    const float* __restrict__ Wk, const float* __restrict__ bk,
    const float* __restrict__ Wv, const float* __restrict__ bv,
    const float* __restrict__ Wo, const float* __restrict__ bo,
    float* __restrict__ out)
{
    __shared__ __align__(16) float buf[4800];    // 19.2 KB: 2 waves x (1440 qkv/out + 960 dist)
    const int tid  = threadIdx.x;
    const int lane = tid & 63;
    const int w    = tid >> 6;                   // wave id: fully independent halves
    const int tokbase = blockIdx.x * 64 + w * TPW;
    float* myBuf = buf + w * 2400;               // 1440 floats: qkv serial -> B0-2 -> out
    float* myD   = buf + w * 2400 + 1440;        // 960 floats: D0, D1

    // Tiny projection weights via uniform (scalar) loads; fold log2(e) into Wq/bq
    // (|.| commutes with the positive scale; softmax Z-norm cancels any scale).
    const float LOG2E = 1.4426950408889634f;
    float wq[9], wk[9], wv[9], bqv[3], bkv[3], bvv[3];
    #pragma unroll
    for (int i = 0; i < 9; ++i) { wq[i] = Wq[i] * LOG2E; wk[i] = Wk[i]; wv[i] = Wv[i]; }
    #pragma unroll
    for (int i = 0; i < 3; ++i) { bqv[i] = bq[i] * LOG2E; bkv[i] = bk[i]; bvv[i] = bv[i]; }
    WAITVM(0);                                   // in case weights came via VMEM

    float a[3][15], b[3][15], vv[3][15];

    stage45(q + (size_t)tokbase * 45, myBuf, lane);   // 6 issues
    WAITVM(0);
    if (lane < TPW) projr<true>(myBuf + lane * 45, wq, bqv, a);
    WAITLG();
    stage45(k + (size_t)tokbase * 45, myBuf, lane);   // 6 issues
    WAITVM(0);
    if (lane < TPW) projr<true>(myBuf + lane * 45, wk, bkv, b);
    WAITLG();

    const float* dbase = dist + (size_t)tokbase * 225;
    const int tok0 = lane / 15, j0 = lane - tok0 * 15;
    const int off0 = tok0 * 225 + j0;

    stage45(v + (size_t)tokbase * 45, myBuf, lane);   // 6   [out 6]
    stage_row(dbase +  0, myD,       off0, j0, lane); // 8   [out 14]
    stage_row(dbase + 15, myD + 480, off0, j0, lane); // 8   [out 22]
    WAITVM(16);                                       // v landed; rows 0-1 fly
    if (lane < TPW) projr<false>(myBuf + lane * 45, wv, bvv, vv);
    WAITLG();                                         // myBuf free
    stage_row(dbase + 30, myBuf,       off0, j0, lane);  // B0  [out <= 24]
    stage_row(dbase + 45, myBuf + 480, off0, j0, lane);  // B1  [32]
    stage_row(dbase + 60, myBuf + 960, off0, j0, lane);  // B2  [40]

    // ---- softmax + PV in registers (5 rows in flight). No max-subtraction:
    // |score*log2e| <= ~52 so exp2 cannot overflow; Z-normalization cancels it.
    float concat[45];                         // concat[n*3+h]
    if (lane < TPW) {
        #pragma unroll
        for (int h = 0; h < 3; ++h) {
            float zp[4] = {0.f, 0.f, 0.f, 0.f};
            float pv[15];
            #pragma unroll
            for (int i = 0; i < 15; ++i) pv[i] = 0.f;
            #pragma unroll
            for (int i = 0; i < 15; ++i)
                #pragma unroll
                for (int j = 0; j < 15; ++j) {
                    float t = EXP2F(a[h][i] * b[h][j]);
                    zp[j & 3] += t;
                    pv[i] = fmaf(t, vv[h][j], pv[i]);
                }
            const float rz = 1.f / ((zp[0] + zp[1]) + (zp[2] + zp[3]));
            #pragma unroll
            for (int i = 0; i < 15; ++i) concat[i*3 + h] = pv[i] * rz;
        }
        #pragma unroll
        for (int h = 0; h < 3; ++h)
            #pragma unroll
            for (int j = 0; j < 15; ++j) vv[h][j] *= 2.f;   // fold 2*distances into v
    }

    // ---- 15 dist rows, ring-5, prefetch distance 5, counted vmcnt ----
    PHASE( 0, 32); PHASE( 1, 32); PHASE( 2, 32); PHASE( 3, 32);
    PHASE( 4, 32); PHASE( 5, 32); PHASE( 6, 32); PHASE( 7, 32);
    PHASE( 8, 32); PHASE( 9, 32); PHASE(10, 32); PHASE(11, 24);
    PHASE(12, 16); PHASE(13, 8);  PHASE(14, 0);
    WAITLG();

    // ---- output projection: Wo/bo via uniform scalar loads ----
    if (lane < TPW) {
        #pragma unroll 3
        for (int o = 0; o < 45; ++o) {
            float acc = bo[o];
            const float* wr = Wo + o * 45;    // uniform address -> s_load
            #pragma unroll
            for (int cc = 0; cc < 45; ++cc) acc = fmaf(concat[cc], wr[cc], acc);
            myBuf[lane * 45 + o] = acc;
        }
    }
    WAITLG();                                 // same-wave ds_writes drained
    {
        float4* o4 = (float4*)(out + (size_t)tokbase * 45);
        const float4* s4 = (const float4*)myBuf;
        #pragma unroll
        for (int it = 0; it < 5; ++it) o4[it * 64 + lane] = s4[it * 64 + lane];
        if (lane < 40) o4[320 + lane] = s4[320 + lane];
    }
}

extern "C" void kernel_launch(void* const* d_in, const int* in_sizes, int n_in,
                              void* d_out, int out_size, void* d_ws, size_t ws_size,
                              hipStream_t stream) {
    const float* q  = (const float*)d_in[0];
    const float* k  = (const float*)d_in[1];
    const float* v  = (const float*)d_in[2];
    const float* ds = (const float*)d_in[3];
    const float* Wq = (const float*)d_in[5];
    const float* bq = (const float*)d_in[6];
    const float* Wk = (const float*)d_in[7];
    const float* bk = (const float*)d_in[8];
    const float* Wv = (const float*)d_in[9];
    const float* bv = (const float*)d_in[10];
    const float* Wo = (const float*)d_in[11];
    const float* bo = (const float*)d_in[12];
    float* out = (float*)d_out;

    // att_val = zeros(4096) at the tail of d_out
    hipMemsetAsync(out + (size_t)32 * 4096 * 45, 0, 4096 * sizeof(float), stream);

    mha_spatial_kernel<<<dim3(2048), dim3(NT), 0, stream>>>(
        q, k, v, ds, Wq, bq, Wk, bk, Wv, bv, Wo, bo, out);
}

// Round 9
// 169.003 us; speedup vs baseline: 1.0018x; 1.0018x over previous
//
#include <hip/hip_runtime.h>

#define NT 128
#define TPW 32   // tokens per wave; 2 independent waves per block, no barriers

#define GL16(gp, lp) __builtin_amdgcn_global_load_lds( \
    (const __attribute__((address_space(1))) void*)(gp), \
    (__attribute__((address_space(3))) void*)(lp), 16, 0, 0)
#define GL4(gp, lp) __builtin_amdgcn_global_load_lds( \
    (const __attribute__((address_space(1))) void*)(gp), \
    (__attribute__((address_space(3))) void*)(lp), 4, 0, 0)
#define WAITVM(N) do { \
    asm volatile("s_waitcnt vmcnt(" #N ")" ::: "memory"); \
    __builtin_amdgcn_sched_barrier(0); \
} while (0)
#define WAITLG() do { \
    asm volatile("s_waitcnt lgkmcnt(0)" ::: "memory"); \
    __builtin_amdgcn_sched_barrier(0); \
} while (0)

#if defined(__has_builtin)
# if __has_builtin(__builtin_amdgcn_exp2f)
#  define EXP2F(x) __builtin_amdgcn_exp2f(x)
# else
#  define EXP2F(x) exp2f(x)
# endif
#else
# define EXP2F(x) exp2f(x)
#endif

// 32 tokens x 45 floats = 360 float4 -> LDS: 5 full GL16 + one 40-lane partial.
__device__ __forceinline__ void stage45(const float* __restrict__ g, float* lds, int lane) {
    const float4* g4 = (const float4*)g;
    #pragma unroll
    for (int it = 0; it < 5; ++it)
        GL16(g4 + it * 64 + lane, lds + it * 256);
    if (lane < 40) GL16(g4 + 320 + lane, lds + 1280);
}

// One dist row r for this wave's 32 tokens = 480 floats: 7 full GL4 + one 32-lane partial.
// m = it*64+lane ; tok=m/15 ; j=m%15 ; off = tok*225+j (row offset folded into dr).
__device__ __forceinline__ void stage_row(const float* __restrict__ dr, float* slot,
                                          int off0, int j0, int lane) {
    int off = off0, j = j0;
    #pragma unroll
    for (int it = 0; it < 7; ++it) {
        GL4(dr + off, slot + it * 64);
        j += 4;
        bool w = (j >= 15);
        j -= w ? 15 : 0;
        off += w ? 1114 : 904;      // wrap: 5*225-11 ; no-wrap: 4*225+4
    }
    if (lane < TPW) GL4(dr + off, slot + 448);   // m = 448+lane, lanes 0-31 only
}

// dst[h][n] = (|.|) sum_d row[d*15+n]*w[h*3+d] + bb[h]
template <bool ABS>
__device__ __forceinline__ void projr(const float* row, const float w[9], const float bb[3],
                                      float dst[3][15]) {
    #pragma unroll
    for (int n = 0; n < 15; ++n) {
        float x0 = row[n], x1 = row[15 + n], x2 = row[30 + n];
        #pragma unroll
        for (int h = 0; h < 3; ++h) {
            float y = fmaf(x2, w[h*3+2], fmaf(x1, w[h*3+1], fmaf(x0, w[h*3+0], bb[h])));
            dst[h][n] = ABS ? fabsf(y) : y;
        }
    }
}

// Ring-5 slot for dist row r: {D0, D1, B0, B1, B2}
#define SLOTP(r) ((r) % 5 == 0 ? myD : (r) % 5 == 1 ? myD + 480 : myBuf + ((r) % 5 - 2) * 480)

// Phase p: counted wait for row p, consume (lanes 0-31), issue row p+5 into same slot.
#define PHASE(p, WN) do { \
    WAITVM(WN); \
    if (lane < TPW) { \
      const float* sl = SLOTP(p) + lane * 15; \
      _Pragma("unroll") \
      for (int jj = 0; jj < 15; ++jj) { \
        float dd = sl[jj]; \
        concat[(p)*3 + 0] = fmaf(dd, vv[0][jj], concat[(p)*3 + 0]); \
        concat[(p)*3 + 1] = fmaf(dd, vv[1][jj], concat[(p)*3 + 1]); \
        concat[(p)*3 + 2] = fmaf(dd, vv[2][jj], concat[(p)*3 + 2]); \
      } } \
    if ((p) <= 9) { WAITLG(); stage_row(dbase + ((p)+5)*15, SLOTP(p), off0, j0, lane); } \
} while (0)

__global__ __launch_bounds__(NT)
__attribute__((amdgpu_waves_per_eu(4, 4)))   // exact range: VGPR budget 512/4 = 128, no 64-squeeze
void mha_spatial_kernel(
    const float* __restrict__ q, const float* __restrict__ k, const float* __restrict__ v,
    const float* __restrict__ dist,
    const float* __restrict__ Wq, const float* __restrict__ bq,
    const float* __restrict__ Wk, const float* __restrict__ bk,
    const float* __restrict__ Wv, const float* __restrict__ bv,
    const float* __restrict__ Wo, const float* __restrict__ bo,
    float* __restrict__ out)
{
    __shared__ __align__(16) float buf[4800];    // 19.2 KB: 2 waves x (1440 qkv/out + 960 dist)
    const int tid  = threadIdx.x;
    const int lane = tid & 63;
    const int w    = tid >> 6;                   // wave id: fully independent halves
    const int tokbase = blockIdx.x * 64 + w * TPW;
    float* myBuf = buf + w * 2400;               // 1440 floats: qkv serial -> B0-2 -> out
    float* myD   = buf + w * 2400 + 1440;        // 960 floats: D0, D1

    // Tiny projection weights via uniform (scalar) loads; fold log2(e) into Wq/bq
    // (|.| commutes with the positive scale; softmax Z-norm cancels any scale).
    const float LOG2E = 1.4426950408889634f;
    float wq[9], wk[9], wv[9], bqv[3], bkv[3], bvv[3];
    #pragma unroll
    for (int i = 0; i < 9; ++i) { wq[i] = Wq[i] * LOG2E; wk[i] = Wk[i]; wv[i] = Wv[i]; }
    #pragma unroll
    for (int i = 0; i < 3; ++i) { bqv[i] = bq[i] * LOG2E; bkv[i] = bk[i]; bvv[i] = bv[i]; }
    WAITVM(0);                                   // in case weights came via VMEM

    float a[3][15], b[3][15], vv[3][15];

    stage45(q + (size_t)tokbase * 45, myBuf, lane);   // 6 issues
    WAITVM(0);
    if (lane < TPW) projr<true>(myBuf + lane * 45, wq, bqv, a);
    WAITLG();
    stage45(k + (size_t)tokbase * 45, myBuf, lane);   // 6 issues
    WAITVM(0);
    if (lane < TPW) projr<true>(myBuf + lane * 45, wk, bkv, b);
    WAITLG();

    const float* dbase = dist + (size_t)tokbase * 225;
    const int tok0 = lane / 15, j0 = lane - tok0 * 15;
    const int off0 = tok0 * 225 + j0;

    stage45(v + (size_t)tokbase * 45, myBuf, lane);   // 6   [out 6]
    stage_row(dbase +  0, myD,       off0, j0, lane); // 8   [out 14]
    stage_row(dbase + 15, myD + 480, off0, j0, lane); // 8   [out 22]
    WAITVM(16);                                       // v landed; rows 0-1 fly
    if (lane < TPW) projr<false>(myBuf + lane * 45, wv, bvv, vv);
    WAITLG();                                         // myBuf free
    stage_row(dbase + 30, myBuf,       off0, j0, lane);  // B0  [out <= 24]
    stage_row(dbase + 45, myBuf + 480, off0, j0, lane);  // B1  [32]
    stage_row(dbase + 60, myBuf + 960, off0, j0, lane);  // B2  [40]

    // ---- softmax + PV in registers (5 rows in flight). No max-subtraction:
    // |score*log2e| <= ~52 so exp2 cannot overflow; Z-normalization cancels it.
    float concat[45];                         // concat[n*3+h]
    if (lane < TPW) {
        #pragma unroll
        for (int h = 0; h < 3; ++h) {
            float zp[4] = {0.f, 0.f, 0.f, 0.f};
            float pv[15];
            #pragma unroll
            for (int i = 0; i < 15; ++i) pv[i] = 0.f;
            #pragma unroll
            for (int i = 0; i < 15; ++i)
                #pragma unroll
                for (int j = 0; j < 15; ++j) {
                    float t = EXP2F(a[h][i] * b[h][j]);
                    zp[j & 3] += t;
                    pv[i] = fmaf(t, vv[h][j], pv[i]);
                }
            const float rz = 1.f / ((zp[0] + zp[1]) + (zp[2] + zp[3]));
            #pragma unroll
            for (int i = 0; i < 15; ++i) concat[i*3 + h] = pv[i] * rz;
        }
        #pragma unroll
        for (int h = 0; h < 3; ++h)
            #pragma unroll
            for (int j = 0; j < 15; ++j) vv[h][j] *= 2.f;   // fold 2*distances into v
    }

    // ---- 15 dist rows, ring-5, prefetch distance 5, counted vmcnt ----
    PHASE( 0, 32); PHASE( 1, 32); PHASE( 2, 32); PHASE( 3, 32);
    PHASE( 4, 32); PHASE( 5, 32); PHASE( 6, 32); PHASE( 7, 32);
    PHASE( 8, 32); PHASE( 9, 32); PHASE(10, 32); PHASE(11, 24);
    PHASE(12, 16); PHASE(13, 8);  PHASE(14, 0);
    WAITLG();

    // ---- output projection: Wo/bo via uniform scalar loads ----
    if (lane < TPW) {
        #pragma unroll 3
        for (int o = 0; o < 45; ++o) {
            float acc = bo[o];
            const float* wr = Wo + o * 45;    // uniform address -> s_load
            #pragma unroll
            for (int cc = 0; cc < 45; ++cc) acc = fmaf(concat[cc], wr[cc], acc);
            myBuf[lane * 45 + o] = acc;
        }
    }
    WAITLG();                                 // same-wave ds_writes drained
    {
        float4* o4 = (float4*)(out + (size_t)tokbase * 45);
        const float4* s4 = (const float4*)myBuf;
        #pragma unroll
        for (int it = 0; it < 5; ++it) o4[it * 64 + lane] = s4[it * 64 + lane];
        if (lane < 40) o4[320 + lane] = s4[320 + lane];
    }
}

extern "C" void kernel_launch(void* const* d_in, const int* in_sizes, int n_in,
                              void* d_out, int out_size, void* d_ws, size_t ws_size,
                              hipStream_t stream) {
    const float* q  = (const float*)d_in[0];
    const float* k  = (const float*)d_in[1];
    const float* v  = (const float*)d_in[2];
    const float* ds = (const float*)d_in[3];
    const float* Wq = (const float*)d_in[5];
    const float* bq = (const float*)d_in[6];
    const float* Wk = (const float*)d_in[7];
    const float* bk = (const float*)d_in[8];
    const float* Wv = (const float*)d_in[9];
    const float* bv = (const float*)d_in[10];
    const float* Wo = (const float*)d_in[11];
    const float* bo = (const float*)d_in[12];
    float* out = (float*)d_out;

    // att_val = zeros(4096) at the tail of d_out
    hipMemsetAsync(out + (size_t)32 * 4096 * 45, 0, 4096 * sizeof(float), stream);

    mha_spatial_kernel<<<dim3(2048), dim3(NT), 0, stream>>>(
        q, k, v, ds, Wq, bq, Wk, bk, Wv, bv, Wo, bo, out);
}

// Round 10
// 85.254 us; speedup vs baseline: 1.9858x; 1.9824x over previous
//
#include <hip/hip_runtime.h>

#define NT 64
#define TPW 32   // tokens per wave; one wave per block (4096 blocks)

#define GL16(gp, lp) __builtin_amdgcn_global_load_lds( \
    (const __attribute__((address_space(1))) void*)(gp), \
    (__attribute__((address_space(3))) void*)(lp), 16, 0, 0)
#define GL4(gp, lp) __builtin_amdgcn_global_load_lds( \
    (const __attribute__((address_space(1))) void*)(gp), \
    (__attribute__((address_space(3))) void*)(lp), 4, 0, 0)
#define WAITVM(N) do { \
    asm volatile("s_waitcnt vmcnt(" #N ")" ::: "memory"); \
    __builtin_amdgcn_sched_barrier(0); \
} while (0)
#define WAITLG() do { \
    asm volatile("s_waitcnt lgkmcnt(0)" ::: "memory"); \
    __builtin_amdgcn_sched_barrier(0); \
} while (0)

#if defined(__has_builtin)
# if __has_builtin(__builtin_amdgcn_exp2f)
#  define EXP2F(x) __builtin_amdgcn_exp2f(x)
# else
#  define EXP2F(x) exp2f(x)
# endif
#else
# define EXP2F(x) exp2f(x)
#endif

// 32 tokens x 45 floats = 360 float4 -> LDS: 5 full GL16 + one 40-lane partial.
__device__ __forceinline__ void stage45(const float* __restrict__ g, float* lds, int lane) {
    const float4* g4 = (const float4*)g;
    #pragma unroll
    for (int it = 0; it < 5; ++it)
        GL16(g4 + it * 64 + lane, lds + it * 256);
    if (lane < 40) GL16(g4 + 320 + lane, lds + 1280);
}

// One dist row r for this wave's 32 tokens = 480 floats: 7 full GL4 + one 32-lane partial.
// m = it*64+lane ; tok=m/15 ; j=m%15 ; off = tok*225+j (row offset folded into dr).
__device__ __forceinline__ void stage_row(const float* __restrict__ dr, float* slot,
                                          int off0, int j0, int lane) {
    int off = off0, j = j0;
    #pragma unroll
    for (int it = 0; it < 7; ++it) {
        GL4(dr + off, slot + it * 64);
        j += 4;
        bool w = (j >= 15);
        j -= w ? 15 : 0;
        off += w ? 1114 : 904;      // wrap: 5*225-11 ; no-wrap: 4*225+4
    }
    if (lane < TPW) GL4(dr + off, slot + 448);   // m = 448+lane, lanes 0-31 only
}

// dst[h][n] = (|.|) sum_d row[d*15+n]*w[h*3+d] + bb[h]
template <bool ABS>
__device__ __forceinline__ void projr(const float* row, const float w[9], const float bb[3],
                                      float dst[3][15]) {
    #pragma unroll
    for (int n = 0; n < 15; ++n) {
        float x0 = row[n], x1 = row[15 + n], x2 = row[30 + n];
        #pragma unroll
        for (int h = 0; h < 3; ++h) {
            float y = fmaf(x2, w[h*3+2], fmaf(x1, w[h*3+1], fmaf(x0, w[h*3+0], bb[h])));
            dst[h][n] = ABS ? fabsf(y) : y;
        }
    }
}

// Ring-5 slot for dist row r: {D0, D1, B0, B1, B2}  (B* = thirds of buf, free post-projv)
#define SLOTP(r) ((r) % 5 == 0 ? myD : (r) % 5 == 1 ? myD + 480 : myBuf + ((r) % 5 - 2) * 480)

// Phase p: counted wait for row p, consume (lanes 0-31), issue row p+5 into same slot.
#define PHASE(p, WN) do { \
    WAITVM(WN); \
    if (lane < TPW) { \
      const float* sl = SLOTP(p) + lane * 15; \
      _Pragma("unroll") \
      for (int jj = 0; jj < 15; ++jj) { \
        float dd = sl[jj]; \
        concat[(p)*3 + 0] = fmaf(dd, vv[0][jj], concat[(p)*3 + 0]); \
        concat[(p)*3 + 1] = fmaf(dd, vv[1][jj], concat[(p)*3 + 1]); \
        concat[(p)*3 + 2] = fmaf(dd, vv[2][jj], concat[(p)*3 + 2]); \
      } } \
    if ((p) <= 9) { WAITLG(); stage_row(dbase + ((p)+5)*15, SLOTP(p), off0, j0, lane); } \
} while (0)

__global__ __launch_bounds__(NT, 2)   // R7-proven regime: VGPR budget 256, allocator picks ~100
void mha_spatial_kernel(
    const float* __restrict__ q, const float* __restrict__ k, const float* __restrict__ v,
    const float* __restrict__ dist,
    const float* __restrict__ Wq, const float* __restrict__ bq,
    const float* __restrict__ Wk, const float* __restrict__ bk,
    const float* __restrict__ Wv, const float* __restrict__ bv,
    const float* __restrict__ Wo, const float* __restrict__ bo,
    float* __restrict__ out)
{
    __shared__ __align__(16) float buf[2400];    // 9.6 KB -> 16 blocks/CU = 16 waves/CU
    const int lane = threadIdx.x;                // one wave per block
    const int tokbase = blockIdx.x * TPW;
    float* myBuf = buf;                          // 1440 floats: qkv serial -> B0-2 -> out
    float* myD   = buf + 1440;                   // 960 floats: D0, D1

    // Tiny projection weights via uniform (scalar) loads. Fold log2(e) into Wq/bq
    // (softmax Z-norm cancels scale; |.| commutes with positive scale) and fold the
    // 2x distance factor into Wv/bv (normalize with 0.5/Z instead of 1/Z).
    const float LOG2E = 1.4426950408889634f;
    float wq[9], wk[9], wv[9], bqv[3], bkv[3], bvv[3];
    #pragma unroll
    for (int i = 0; i < 9; ++i) { wq[i] = Wq[i] * LOG2E; wk[i] = Wk[i]; wv[i] = Wv[i] * 2.f; }
    #pragma unroll
    for (int i = 0; i < 3; ++i) { bqv[i] = bq[i] * LOG2E; bkv[i] = bk[i]; bvv[i] = bv[i] * 2.f; }

    float a[3][15], b[3][15], vv[3][15];

    stage45(q + (size_t)tokbase * 45, myBuf, lane);   // 6 issues
    WAITVM(0);
    if (lane < TPW) projr<true>(myBuf + lane * 45, wq, bqv, a);
    WAITLG();
    stage45(k + (size_t)tokbase * 45, myBuf, lane);   // 6 issues
    WAITVM(0);
    if (lane < TPW) projr<true>(myBuf + lane * 45, wk, bkv, b);
    WAITLG();

    const float* dbase = dist + (size_t)tokbase * 225;
    const int tok0 = lane / 15, j0 = lane - tok0 * 15;
    const int off0 = tok0 * 225 + j0;

    stage45(v + (size_t)tokbase * 45, myBuf, lane);   // 6   [out 6]
    stage_row(dbase +  0, myD,       off0, j0, lane); // 8   [out 14]
    stage_row(dbase + 15, myD + 480, off0, j0, lane); // 8   [out 22]
    WAITVM(16);                                       // v landed; rows 0-1 fly
    if (lane < TPW) projr<false>(myBuf + lane * 45, wv, bvv, vv);   // vv = 2*vh
    WAITLG();                                         // myBuf free
    stage_row(dbase + 30, myBuf,       off0, j0, lane);  // B0  [out <= 24]
    stage_row(dbase + 45, myBuf + 480, off0, j0, lane);  // B1  [32]
    stage_row(dbase + 60, myBuf + 960, off0, j0, lane);  // B2  [40]

    // ---- softmax + PV in registers (5 rows in flight). No max-subtraction:
    // |score*log2e| <= ~52 so exp2 cannot overflow; Z-normalization cancels it.
    // vv carries the 2x dist factor, so P.v uses rz = 0.5/Z.
    float concat[45];                         // concat[n*3+h]
    if (lane < TPW) {
        #pragma unroll
        for (int h = 0; h < 3; ++h) {
            float zp[4] = {0.f, 0.f, 0.f, 0.f};
            float pv[15];
            #pragma unroll
            for (int i = 0; i < 15; ++i) pv[i] = 0.f;
            #pragma unroll
            for (int i = 0; i < 15; ++i)
                #pragma unroll
                for (int j = 0; j < 15; ++j) {
                    float t = EXP2F(a[h][i] * b[h][j]);
                    zp[j & 3] += t;
                    pv[i] = fmaf(t, vv[h][j], pv[i]);
                }
            const float rz = 0.5f / ((zp[0] + zp[1]) + (zp[2] + zp[3]));
            #pragma unroll
            for (int i = 0; i < 15; ++i) concat[i*3 + h] = pv[i] * rz;
        }
    }

    // ---- 15 dist rows, ring-5, prefetch distance 5, counted vmcnt ----
    PHASE( 0, 32); PHASE( 1, 32); PHASE( 2, 32); PHASE( 3, 32);
    PHASE( 4, 32); PHASE( 5, 32); PHASE( 6, 32); PHASE( 7, 32);
    PHASE( 8, 32); PHASE( 9, 32); PHASE(10, 32); PHASE(11, 24);
    PHASE(12, 16); PHASE(13, 8);  PHASE(14, 0);
    WAITLG();

    // ---- output projection: Wo/bo via uniform scalar loads ----
    if (lane < TPW) {
        #pragma unroll 3
        for (int o = 0; o < 45; ++o) {
            float acc = bo[o];
            const float* wr = Wo + o * 45;    // uniform address -> s_load
            #pragma unroll
            for (int cc = 0; cc < 45; ++cc) acc = fmaf(concat[cc], wr[cc], acc);
            myBuf[lane * 45 + o] = acc;
        }
    }
    WAITLG();                                 // same-wave ds_writes drained
    {
        float4* o4 = (float4*)(out + (size_t)tokbase * 45);
        const float4* s4 = (const float4*)myBuf;
        #pragma unroll
        for (int it = 0; it < 5; ++it) o4[it * 64 + lane] = s4[it * 64 + lane];
        if (lane < 40) o4[320 + lane] = s4[320 + lane];
    }
}

extern "C" void kernel_launch(void* const* d_in, const int* in_sizes, int n_in,
                              void* d_out, int out_size, void* d_ws, size_t ws_size,
                              hipStream_t stream) {
    const float* q  = (const float*)d_in[0];
    const float* k  = (const float*)d_in[1];
    const float* v  = (const float*)d_in[2];
    const float* ds = (const float*)d_in[3];
    const float* Wq = (const float*)d_in[5];
    const float* bq = (const float*)d_in[6];
    const float* Wk = (const float*)d_in[7];
    const float* bk = (const float*)d_in[8];
    const float* Wv = (const float*)d_in[9];
    const float* bv = (const float*)d_in[10];
    const float* Wo = (const float*)d_in[11];
    const float* bo = (const float*)d_in[12];
    float* out = (float*)d_out;

    // att_val = zeros(4096) at the tail of d_out
    hipMemsetAsync(out + (size_t)32 * 4096 * 45, 0, 4096 * sizeof(float), stream);

    mha_spatial_kernel<<<dim3((32 * 4096) / TPW), dim3(NT), 0, stream>>>(
        q, k, v, ds, Wq, bq, Wk, bk, Wv, bv, Wo, bo, out);
}